// Round 1
// baseline (47.682 us; speedup 1.0000x reference)
//
#include <hip/hip_runtime.h>

#define DIM 1024
#define EPS 1e-5f

static __device__ __forceinline__ float4 f4_mul(float4 a, float4 b) {
    return make_float4(a.x * b.x, a.y * b.y, a.z * b.z, a.w * b.w);
}
static __device__ __forceinline__ float4 f4_add(float4 a, float4 b) {
    return make_float4(a.x + b.x, a.y + b.y, a.z + b.z, a.w + b.w);
}
static __device__ __forceinline__ float4 f4_sub(float4 a, float4 b) {
    return make_float4(a.x - b.x, a.y - b.y, a.z - b.z, a.w - b.w);
}
static __device__ __forceinline__ float4 f4_scale(float4 a, float s) {
    return make_float4(a.x * s, a.y * s, a.z * s, a.w * s);
}

// One wave (64 lanes) per row of 1024 floats.
// Element index e (10 bits) decomposition:
//   e = j*256 + lane*4 + c   -> bits[1:0]=c (float4 comp), bits[7:2]=lane, bits[9:8]=j
// FHT = independent 2-pt butterflies per bit (they commute):
//   bits 0,1  -> inside each float4 (registers)
//   bits 2..7 -> __shfl_xor masks 1..32
//   bits 8,9  -> across the 4 float4s (registers)
__global__ __launch_bounds__(256) void fht_golay_kernel(
    const float* __restrict__ x,
    const float* __restrict__ golay,
    const float* __restrict__ alpha,
    float* __restrict__ out,
    int nrows)
{
    const int lane = threadIdx.x & 63;
    const int wave = threadIdx.x >> 6;
    const int row  = blockIdx.x * 4 + wave;
    if (row >= nrows) return;

    const float scale = 1.0f / (alpha[0] + EPS);

    const float4* __restrict__ xr = reinterpret_cast<const float4*>(x + (size_t)row * DIM);
    const float4* __restrict__ gr = reinterpret_cast<const float4*>(golay);

    float4 v[4];
#pragma unroll
    for (int j = 0; j < 4; ++j) {
        float4 xv = xr[j * 64 + lane];
        float4 gv = gr[j * 64 + lane];
        v[j] = f4_mul(xv, gv);
    }

    // ---- bits 0,1: butterflies inside each float4 ----
#pragma unroll
    for (int j = 0; j < 4; ++j) {
        float a0 = v[j].x, a1 = v[j].y, a2 = v[j].z, a3 = v[j].w;
        // h=1: (0,1),(2,3)
        float b0 = a0 + a1, b1 = a0 - a1, b2 = a2 + a3, b3 = a2 - a3;
        // h=2: (0,2),(1,3)
        v[j].x = b0 + b2;
        v[j].y = b1 + b3;
        v[j].z = b0 - b2;
        v[j].w = b1 - b3;
    }

    // ---- bits 2..7: cross-lane butterflies via shfl_xor ----
    // partner value o = shfl_xor(v, m); lane with bit clear: v+o; bit set: o-v.
#pragma unroll
    for (int m = 1; m <= 32; m <<= 1) {
        const float s = (lane & m) ? -1.0f : 1.0f;
#pragma unroll
        for (int j = 0; j < 4; ++j) {
            float ox = __shfl_xor(v[j].x, m, 64);
            float oy = __shfl_xor(v[j].y, m, 64);
            float oz = __shfl_xor(v[j].z, m, 64);
            float ow = __shfl_xor(v[j].w, m, 64);
            v[j].x = fmaf(s, v[j].x, ox);
            v[j].y = fmaf(s, v[j].y, oy);
            v[j].z = fmaf(s, v[j].z, oz);
            v[j].w = fmaf(s, v[j].w, ow);
        }
    }

    // ---- bits 8,9: butterflies across the 4 float4s ----
    {
        // h=256: j pairs (0,1),(2,3)
        float4 a = v[0], b = v[1], c = v[2], d = v[3];
        float4 p0 = f4_add(a, b), p1 = f4_sub(a, b);
        float4 p2 = f4_add(c, d), p3 = f4_sub(c, d);
        // h=512: j pairs (0,2),(1,3)
        v[0] = f4_add(p0, p2);
        v[1] = f4_add(p1, p3);
        v[2] = f4_sub(p0, p2);
        v[3] = f4_sub(p1, p3);
    }

    float4* __restrict__ orow = reinterpret_cast<float4*>(out + (size_t)row * DIM);
#pragma unroll
    for (int j = 0; j < 4; ++j) {
        orow[j * 64 + lane] = f4_scale(v[j], scale);
    }
}

extern "C" void kernel_launch(void* const* d_in, const int* in_sizes, int n_in,
                              void* d_out, int out_size, void* d_ws, size_t ws_size,
                              hipStream_t stream) {
    const float* x     = (const float*)d_in[0];
    const float* golay = (const float*)d_in[1];
    const float* alpha = (const float*)d_in[2];
    float* out = (float*)d_out;

    const int nrows = in_sizes[0] / DIM;           // 4*8192 = 32768
    const int rows_per_block = 4;                  // 256 threads = 4 waves
    const int grid = (nrows + rows_per_block - 1) / rows_per_block;

    fht_golay_kernel<<<grid, 256, 0, stream>>>(x, golay, alpha, out, nrows);
}

// Round 4
// 44.481 us; speedup vs baseline: 1.0720x; 1.0720x over previous
//
#include <hip/hip_runtime.h>

#define DIM 1024
#define EPS 1e-5f

typedef float fx4 __attribute__((ext_vector_type(4)));         // native vector for nontemporal builtin
typedef unsigned int ux2 __attribute__((ext_vector_type(2)));  // permlane*_swap result

static __device__ __forceinline__ float4 f4_mul(float4 a, float4 b) {
    return make_float4(a.x * b.x, a.y * b.y, a.z * b.z, a.w * b.w);
}
static __device__ __forceinline__ float4 f4_add(float4 a, float4 b) {
    return make_float4(a.x + b.x, a.y + b.y, a.z + b.z, a.w + b.w);
}
static __device__ __forceinline__ float4 f4_sub(float4 a, float4 b) {
    return make_float4(a.x - b.x, a.y - b.y, a.z - b.z, a.w - b.w);
}

// ---- cross-lane exchange primitives ----
// xor 1 / xor 2: DPP quad_perm (VALU pipe)
static __device__ __forceinline__ float dpp_xor1(float v) {
    return __int_as_float(__builtin_amdgcn_mov_dpp(__float_as_int(v), 0xB1, 0xF, 0xF, 0)); // [1,0,3,2]
}
static __device__ __forceinline__ float dpp_xor2(float v) {
    return __int_as_float(__builtin_amdgcn_mov_dpp(__float_as_int(v), 0x4E, 0xF, 0xF, 0)); // [2,3,0,1]
}
// xor 4 / xor 8: ds_swizzle BitMode (DS pipe)
static __device__ __forceinline__ float swz_xor4(float v) {
    return __int_as_float(__builtin_amdgcn_ds_swizzle(__float_as_int(v), 0x101F)); // xor=4,and=0x1F
}
static __device__ __forceinline__ float swz_xor8(float v) {
    return __int_as_float(__builtin_amdgcn_ds_swizzle(__float_as_int(v), 0x201F)); // xor=8,and=0x1F
}
// xor 16 / xor 32: gfx950 permlane swap builtins (VALU pipe), SSA-safe.
// permlane16_swap(v,v): r.x = even-row value for this 16-lane row pair (self if even
// row, partner if odd), r.y = odd-row value. So out = r.x + s*r.y is the butterfly.
static __device__ __forceinline__ float bfly16(float v, float s) {
    ux2 r = __builtin_amdgcn_permlane16_swap(__float_as_uint(v), __float_as_uint(v), false, false);
    return fmaf(s, __uint_as_float(r.y), __uint_as_float(r.x));
}
static __device__ __forceinline__ float bfly32(float v, float s) {
    ux2 r = __builtin_amdgcn_permlane32_swap(__float_as_uint(v), __float_as_uint(v), false, false);
    return fmaf(s, __uint_as_float(r.y), __uint_as_float(r.x));
}

// One wave (64 lanes) per row of 1024 floats.
// e = j*256 + lane*4 + c : bits[1:0]=c (float4 comp), bits[7:2]=lane, bits[9:8]=j
// Butterfly stages (commute): bits 0,1 in-reg; bits 2..7 cross-lane; bits 8,9 in-reg.
__global__ __launch_bounds__(256) void fht_golay_kernel(
    const float* __restrict__ x,
    const float* __restrict__ golay,
    const float* __restrict__ alpha,
    float* __restrict__ out,
    int nrows)
{
    const int lane = threadIdx.x & 63;
    const int wave = threadIdx.x >> 6;
    const int row  = blockIdx.x * 4 + wave;
    if (row >= nrows) return;

    const float scale = 1.0f / (alpha[0] + EPS);

    const float4* __restrict__ xr = reinterpret_cast<const float4*>(x + (size_t)row * DIM);
    const float4* __restrict__ gr = reinterpret_cast<const float4*>(golay);

    float4 v[4];
#pragma unroll
    for (int j = 0; j < 4; ++j) {
        float4 xv = xr[j * 64 + lane];
        float4 gv = gr[j * 64 + lane];
        v[j] = f4_mul(xv, gv);
    }

    // ---- bits 0,1: butterflies inside each float4 ----
#pragma unroll
    for (int j = 0; j < 4; ++j) {
        float a0 = v[j].x, a1 = v[j].y, a2 = v[j].z, a3 = v[j].w;
        float b0 = a0 + a1, b1 = a0 - a1, b2 = a2 + a3, b3 = a2 - a3;
        v[j].x = b0 + b2;
        v[j].y = b1 + b3;
        v[j].z = b0 - b2;
        v[j].w = b1 - b3;
    }

    // ---- bits 2..7: cross-lane butterflies ----
    // partner o of v_old; v_new = o + s*v_old  (bit clear: sum; bit set: partner - self)
    {
        const float s1 = (lane & 1) ? -1.0f : 1.0f;
#pragma unroll
        for (int j = 0; j < 4; ++j) {
            v[j].x = fmaf(s1, v[j].x, dpp_xor1(v[j].x));
            v[j].y = fmaf(s1, v[j].y, dpp_xor1(v[j].y));
            v[j].z = fmaf(s1, v[j].z, dpp_xor1(v[j].z));
            v[j].w = fmaf(s1, v[j].w, dpp_xor1(v[j].w));
        }
    }
    {
        const float s2 = (lane & 2) ? -1.0f : 1.0f;
#pragma unroll
        for (int j = 0; j < 4; ++j) {
            v[j].x = fmaf(s2, v[j].x, dpp_xor2(v[j].x));
            v[j].y = fmaf(s2, v[j].y, dpp_xor2(v[j].y));
            v[j].z = fmaf(s2, v[j].z, dpp_xor2(v[j].z));
            v[j].w = fmaf(s2, v[j].w, dpp_xor2(v[j].w));
        }
    }
    {
        const float s4 = (lane & 4) ? -1.0f : 1.0f;
#pragma unroll
        for (int j = 0; j < 4; ++j) {
            v[j].x = fmaf(s4, v[j].x, swz_xor4(v[j].x));
            v[j].y = fmaf(s4, v[j].y, swz_xor4(v[j].y));
            v[j].z = fmaf(s4, v[j].z, swz_xor4(v[j].z));
            v[j].w = fmaf(s4, v[j].w, swz_xor4(v[j].w));
        }
    }
    {
        const float s8 = (lane & 8) ? -1.0f : 1.0f;
#pragma unroll
        for (int j = 0; j < 4; ++j) {
            v[j].x = fmaf(s8, v[j].x, swz_xor8(v[j].x));
            v[j].y = fmaf(s8, v[j].y, swz_xor8(v[j].y));
            v[j].z = fmaf(s8, v[j].z, swz_xor8(v[j].z));
            v[j].w = fmaf(s8, v[j].w, swz_xor8(v[j].w));
        }
    }
    {
        const float s16 = (lane & 16) ? -1.0f : 1.0f;
#pragma unroll
        for (int j = 0; j < 4; ++j) {
            v[j].x = bfly16(v[j].x, s16);
            v[j].y = bfly16(v[j].y, s16);
            v[j].z = bfly16(v[j].z, s16);
            v[j].w = bfly16(v[j].w, s16);
        }
    }
    {
        const float s32 = (lane & 32) ? -1.0f : 1.0f;
#pragma unroll
        for (int j = 0; j < 4; ++j) {
            v[j].x = bfly32(v[j].x, s32);
            v[j].y = bfly32(v[j].y, s32);
            v[j].z = bfly32(v[j].z, s32);
            v[j].w = bfly32(v[j].w, s32);
        }
    }

    // ---- bits 8,9: butterflies across the 4 float4s ----
    {
        float4 a = v[0], b = v[1], c = v[2], d = v[3];
        float4 p0 = f4_add(a, b), p1 = f4_sub(a, b);
        float4 p2 = f4_add(c, d), p3 = f4_sub(c, d);
        v[0] = f4_add(p0, p2);
        v[1] = f4_add(p1, p3);
        v[2] = f4_sub(p0, p2);
        v[3] = f4_sub(p1, p3);
    }

    // ---- nontemporal streaming store: don't evict x from L3 ----
    fx4* __restrict__ orow = reinterpret_cast<fx4*>(out + (size_t)row * DIM);
#pragma unroll
    for (int j = 0; j < 4; ++j) {
        fx4 sv;
        sv.x = v[j].x * scale;
        sv.y = v[j].y * scale;
        sv.z = v[j].z * scale;
        sv.w = v[j].w * scale;
        __builtin_nontemporal_store(sv, &orow[j * 64 + lane]);
    }
}

extern "C" void kernel_launch(void* const* d_in, const int* in_sizes, int n_in,
                              void* d_out, int out_size, void* d_ws, size_t ws_size,
                              hipStream_t stream) {
    const float* x     = (const float*)d_in[0];
    const float* golay = (const float*)d_in[1];
    const float* alpha = (const float*)d_in[2];
    float* out = (float*)d_out;

    const int nrows = in_sizes[0] / DIM;           // 4*8192 = 32768
    const int rows_per_block = 4;                  // 256 threads = 4 waves
    const int grid = (nrows + rows_per_block - 1) / rows_per_block;

    fht_golay_kernel<<<grid, 256, 0, stream>>>(x, golay, alpha, out, nrows);
}